// Round 9
// baseline (283.882 us; speedup 1.0000x reference)
//
#include <hip/hip_runtime.h>
#include <stdint.h>

#define NGRAPH 512
#define NPG    152
#define NNODES (NGRAPH*NPG)     // 77824
#define DEG    8
#define EPG    (NPG*DEG)        // 1216 edges per graph
#define NEDGE  (NNODES*DEG)     // 622592
#define CCH    192
#define HEADS  6
#define HID    32
#define NSEG   (NPG+EPG)        // 1368 slots = edges + self loops
#define PST    168              // P/Ht row stride (bf16 elems): 336B -> 2-way bank (free)

typedef __attribute__((ext_vector_type(8))) short short8v;
typedef __attribute__((ext_vector_type(4))) float f32x4;
typedef __attribute__((ext_vector_type(4))) unsigned short ushort4v;

__device__ __forceinline__ unsigned short f2bf(float f){
  union { float f; uint32_t u; } x; x.f = f;
  uint32_t u = x.u;
  return (unsigned short)((u + 0x7fffu + ((u >> 16) & 1u)) >> 16); // RNE
}
__device__ __forceinline__ float bitsf(uint32_t b){
  union { uint32_t u; float f; } x; x.u = b; return x.f;
}
__device__ __forceinline__ void gload_lds16(const void* g, void* l){
  __builtin_amdgcn_global_load_lds((const __attribute__((address_space(1))) void*)g,
                                   (__attribute__((address_space(3))) void*)l, 16, 0, 0);
}

// ---- W1[K][192] f32 -> Wt1[192][128] bf16 ; W2 -> Wt2[192][192] ----
__global__ void wprep_all(const float* __restrict__ W1, const float* __restrict__ W2,
                          unsigned short* __restrict__ Wt1, unsigned short* __restrict__ Wt2){
  int idx = blockIdx.x*256 + threadIdx.x;
  if (idx < CCH*128){
    int c = idx >> 7, k = idx & 127;
    Wt1[idx] = f2bf(W1[k*CCH + c]);
  } else if (idx < CCH*(128+192)){
    int j = idx - CCH*128;
    int c = j/192, k = j - c*192;
    Wt2[j] = f2bf(W2[k*CCH + c]);
  }
}

// ---- per-graph CSR + duplicate merge: slot -> (s | mult<<8 | d<<16); null = d=152 ----
// Duplicate (s,d) edges (random graph => ~32/graph, plus self-loop collisions) MUST
// contribute multiplicity to both softmax denom and numerator (reference sums per edge).
__global__ __launch_bounds__(256) void pack_build(const int* __restrict__ esrc,
    const int* __restrict__ edst, unsigned int* __restrict__ gpack){
  __shared__ int cnt[256];
  __shared__ int woff[NPG];
  __shared__ unsigned short slots[NSEG];
  const int g = blockIdx.x, t = threadIdx.x, base = g*NPG;

  cnt[t] = (t < NPG) ? 1 : 0;            // self loop pre-counted
  __syncthreads();

  int es[5], ed[5];
  #pragma unroll
  for (int u=0;u<5;u++){
    int i = t + u*256;
    es[u] = -1; ed[u] = -1;
    if (i < EPG){
      es[u] = esrc[g*EPG+i] - base;
      ed[u] = edst[g*EPG+i] - base;
      atomicAdd(&cnt[ed[u]], 1);
    }
  }
  __syncthreads();
  for (int off=1; off<256; off<<=1){
    int a = cnt[t];
    int b = (t>=off) ? cnt[t-off] : 0;
    __syncthreads();
    cnt[t] = a + b;
    __syncthreads();
  }
  if (t < NPG) woff[t] = (t==0) ? 0 : cnt[t-1];
  __syncthreads();
  #pragma unroll
  for (int u=0;u<5;u++){
    if (ed[u] >= 0){
      int pos = atomicAdd(&woff[ed[u]], 1);
      slots[pos] = (unsigned short)es[u];
    }
  }
  if (t < NPG){
    int pos = atomicAdd(&woff[t], 1);
    slots[pos] = (unsigned short)t;
  }
  __syncthreads();
  // merge duplicates within this dst's segment (avg len ~9)
  if (t < NPG){
    int st = (t==0) ? 0 : cnt[t-1], en = cnt[t];
    unsigned int* out = gpack + (size_t)g*NSEG;
    int m = st;
    for (int j=st; j<en; j++){
      int s = (int)slots[j];
      bool first = true;
      for (int k=st; k<j; k++) if ((int)slots[k]==s){ first=false; break; }
      if (first){
        int mult = 1;
        for (int k=j+1; k<en; k++) if ((int)slots[k]==s) mult++;
        out[m++] = (unsigned)s | ((unsigned)mult<<8) | ((unsigned)t<<16);
      }
    }
    for (; m<en; m++) out[m] = (152u<<16);              // null: row 152 (discarded), mult 0
  }
}

// ---- GEMM: H[M,192] = A[M,K] @ W  (unchanged) ----
template<int K, bool A_BF16>
__global__ __launch_bounds__(256) void gemm_mfma(const void* __restrict__ Ap,
    const unsigned short* __restrict__ Bt, unsigned short* __restrict__ H){
  __shared__ unsigned short lA[64*K];
  __shared__ unsigned short lB[96*K];
  const int t  = threadIdx.x;
  const int m0 = blockIdx.x*64, c0 = blockIdx.y*96;

  if (A_BF16){
    const unsigned short* A = (const unsigned short*)Ap + (size_t)m0*K;
    const int CH = 64*K/8;
    for (int i=t; i<CH; i+=256){
      int o   = i*16;
      int row = o / (2*K);
      int db  = o - row*(2*K);
      int sc  = (db>>4) ^ (row&7);
      gload_lds16(A + (size_t)row*K + sc*8, lA + (size_t)(i-(t&63))*8);
    }
  } else {
    const float* A = (const float*)Ap;
    const int KC = K/8;
    for (int i=t; i<64*KC; i+=256){
      int row = i/KC, c8 = i - row*KC;
      const float* p = A + (size_t)(m0+row)*K + c8*8;
      float4 v0 = *(const float4*)p;
      float4 v1 = *(const float4*)(p+4);
      short8v pk;
      pk[0]=(short)f2bf(v0.x); pk[1]=(short)f2bf(v0.y); pk[2]=(short)f2bf(v0.z); pk[3]=(short)f2bf(v0.w);
      pk[4]=(short)f2bf(v1.x); pk[5]=(short)f2bf(v1.y); pk[6]=(short)f2bf(v1.z); pk[7]=(short)f2bf(v1.w);
      *(short8v*)((char*)lA + row*(2*K) + ((c8*16) ^ ((row&7)<<4))) = pk;
    }
  }
  {
    const unsigned short* Bg = Bt + (size_t)c0*K;
    const int CH = 96*K/8;
    for (int i=t; i<CH; i+=256){
      int o   = i*16;
      int row = o / (2*K);
      int db  = o - row*(2*K);
      int sc  = (db>>4) ^ (row&7);
      gload_lds16(Bg + (size_t)row*K + sc*8, lB + (size_t)(i-(t&63))*8);
    }
  }
  __syncthreads();

  const int wid = t>>6, l = t&63;
  const int wr = wid>>1, wc = wid&1;
  const int r16 = l&15, kq = l>>4;
  f32x4 acc[2][3] = {};
  #pragma unroll
  for (int kk=0; kk<K/32; kk++){
    const int chunk = kk*4 + kq;
    short8v af[2], bf[3];
    #pragma unroll
    for (int m=0;m<2;m++){
      int row = wr*32 + m*16 + r16;
      af[m] = *(const short8v*)((const char*)lA + row*(2*K) + ((chunk*16) ^ ((row&7)<<4)));
    }
    #pragma unroll
    for (int n=0;n<3;n++){
      int col = wc*48 + n*16 + r16;
      bf[n] = *(const short8v*)((const char*)lB + col*(2*K) + ((chunk*16) ^ ((col&7)<<4)));
    }
    #pragma unroll
    for (int m=0;m<2;m++)
      #pragma unroll
      for (int n=0;n<3;n++)
        acc[m][n] = __builtin_amdgcn_mfma_f32_16x16x32_bf16(af[m], bf[n], acc[m][n], 0,0,0);
  }
  const int crow = (l>>4)*4;
  #pragma unroll
  for (int m=0;m<2;m++){
    #pragma unroll
    for (int n=0;n<3;n++){
      int colg = c0 + wc*48 + n*16 + r16;
      #pragma unroll
      for (int r=0;r<4;r++){
        int rowg = m0 + wr*32 + m*16 + crow + r;
        H[(size_t)rowg*CCH + colg] = f2bf(acc[m][n][r]);
      }
    }
  }
}

// ---- fused GAT via dense-P MFMA:  out[n,c] = sum_s P[n,s]*H[s,c],  den = out[:,32] ----
// one block per (graph, head); 512 threads (8 waves)
template<bool OUT_BF16>
__global__ __launch_bounds__(512) void gat_fused(
    const unsigned short* __restrict__ H,
    const unsigned int* __restrict__ gpack,
    const float* __restrict__ a_src, const float* __restrict__ a_dst,
    const float* __restrict__ bias, const float* __restrict__ gw,
    const float* __restrict__ gb, const float* __restrict__ gms,
    void* __restrict__ OUTp)
{
  __shared__ __align__(16) char arena[160*PST*2];       // P bf16 [160][168]; later outf f32 [152][36]
  __shared__ __align__(16) unsigned short Ht[48*PST];   // H^T bf16 [48][168]; row32 = ones (den)
  __shared__ __align__(16) unsigned int lpack[NSEG];
  __shared__ float als[160], ald[160];                  // padded so null slots (d=152) read in-bounds
  __shared__ float4 ps[16][8];
  __shared__ float4 mred4[8], vred4[8];

  unsigned short* P = (unsigned short*)arena;
  float* outf = (float*)arena;                          // 152*36*4 = 21.9KB <= 53.8KB

  const int t    = threadIdx.x;
  const int g    = blockIdx.x & 511;
  const int hd   = blockIdx.x >> 9;
  const int base = g*NPG;

  // ---- phase 0: stage pack; zero P and Ht; zero als/ald tail ----
  if (t < NSEG/4)                                        // 342 16B chunks
    gload_lds16(gpack + (size_t)g*NSEG + t*4, lpack + (size_t)(t-(t&63))*4);
  for (int i=t; i<160*PST/8; i+=512) *(int4*)(P  + i*8) = int4{0,0,0,0};
  for (int i=t; i< 48*PST/8; i+=512) *(int4*)(Ht + i*8) = int4{0,0,0,0};
  if (t < 8){ als[NPG+t] = 0.f; ald[NPG+t] = 0.f; }
  __syncthreads();

  // ---- phase 1: load h (bf16), write Ht transposed (raw u16), fused logits ----
  const int c8c = t&3, nb = t>>2;                        // (node, channel-octet)
  const int ab = hd*HID + c8c*8;
  const float4 avs0 = *(const float4*)&a_src[ab];
  const float4 avs1 = *(const float4*)&a_src[ab+4];
  const float4 avd0 = *(const float4*)&a_dst[ab];
  const float4 avd1 = *(const float4*)&a_dst[ab+4];
  #pragma unroll
  for (int it=0; it<2; it++){
    int n = nb + it*128;
    if (n < NPG){
      int4 v = *(const int4*)(H + (size_t)(base+n)*CCH + hd*HID + c8c*8);
      uint32_t w0=(uint32_t)v.x, w1=(uint32_t)v.y, w2=(uint32_t)v.z, w3=(uint32_t)v.w;
      unsigned short* hb = Ht + (c8c*8)*PST + n;
      hb[0*PST]=(unsigned short)(w0&0xffff); hb[1*PST]=(unsigned short)(w0>>16);
      hb[2*PST]=(unsigned short)(w1&0xffff); hb[3*PST]=(unsigned short)(w1>>16);
      hb[4*PST]=(unsigned short)(w2&0xffff); hb[5*PST]=(unsigned short)(w2>>16);
      hb[6*PST]=(unsigned short)(w3&0xffff); hb[7*PST]=(unsigned short)(w3>>16);
      float4 lo = { bitsf(w0<<16), bitsf(w0&0xffff0000u), bitsf(w1<<16), bitsf(w1&0xffff0000u) };
      float4 hi = { bitsf(w2<<16), bitsf(w2&0xffff0000u), bitsf(w3<<16), bitsf(w3&0xffff0000u) };
      float s1 = lo.x*avs0.x + lo.y*avs0.y + lo.z*avs0.z + lo.w*avs0.w
               + hi.x*avs1.x + hi.y*avs1.y + hi.z*avs1.z + hi.w*avs1.w;
      float s2 = lo.x*avd0.x + lo.y*avd0.y + lo.z*avd0.z + lo.w*avd0.w
               + hi.x*avd1.x + hi.y*avd1.y + hi.z*avd1.z + hi.w*avd1.w;
      s1 += __shfl_xor(s1, 1); s1 += __shfl_xor(s1, 2);
      s2 += __shfl_xor(s2, 1); s2 += __shfl_xor(s2, 2);
      if (c8c == 0){ als[n] = s1; ald[n] = s2; }
    }
  }
  if (t < NPG) Ht[32*PST + t] = 0x3F80;                  // ones row -> den column
  __syncthreads();

  // ---- phase 2: scatter P[d][s] = bf16(mult * exp(leakyrelu(als[s]+ald[d]))) ----
  for (int i=t; i<NSEG; i+=512){
    unsigned int pk = lpack[i];
    int s    = (int)(pk & 0xffu);
    int mult = (int)((pk>>8) & 0xffu);
    int d    = (int)(pk >> 16);
    float e = als[s] + ald[d];
    e = (e>0.f) ? e : 0.2f*e;
    float ex = (float)mult * __expf(e);
    P[d*PST + s] = f2bf(ex);
  }
  __syncthreads();

  // ---- phase 3: MFMA  out(160x48) = P(160x160) x Ht^T ; 30 mn-tiles over 8 waves ----
  const int wid = t>>6, l = t&63, r16 = l&15, kq = l>>4;
  f32x4 accs[4] = {};
  #pragma unroll
  for (int a=0; a<4; a++){
    int ti = wid + a*8;
    if (ti < 30){
      int nt = (ti >= 20) ? 2 : ((ti >= 10) ? 1 : 0);
      int mt = ti - nt*10;
      #pragma unroll
      for (int k=0; k<5; k++){
        short8v af = *(const short8v*)(P  + (mt*16 + r16)*PST + (k*4 + kq)*8);
        short8v bf = *(const short8v*)(Ht + (nt*16 + r16)*PST + (k*4 + kq)*8);
        accs[a] = __builtin_amdgcn_mfma_f32_16x16x32_bf16(af, bf, accs[a], 0,0,0);
      }
    }
  }
  __syncthreads();                                       // P now dead

  // ---- phase 4: C fragments -> outf[152][36] (cols 0..31 = unnorm agg, col 32 = den) ----
  #pragma unroll
  for (int a=0; a<4; a++){
    int ti = wid + a*8;
    if (ti < 30){
      int nt = (ti >= 20) ? 2 : ((ti >= 10) ? 1 : 0);
      int mt = ti - nt*10;
      int col = nt*16 + r16;
      if (col < 33){
        #pragma unroll
        for (int r=0; r<4; r++){
          int row = mt*16 + kq*4 + r;
          if (row < NPG) outf[row*36 + col] = accs[a][r];
        }
      }
    }
  }
  __syncthreads();

  // ---- phase 5: /den + bias + ELU + GraphNorm + store.  64 owners x 8 chan-quads ----
  const int lane32 = t & 31, grp16 = t >> 5;
  const int sub = lane32 >> 3, c8 = lane32 & 7;
  const int o = grp16*4 + sub;                           // owner 0..63; nodes o, o+64, o+128
  const int cb = hd*HID + c8*4;
  const float4 bs4 = *(const float4*)&bias[cb];
  const float4 gw4 = *(const float4*)&gw[cb];
  const float4 gb4 = *(const float4*)&gb[cb];
  const float4 ms4 = *(const float4*)&gms[cb];

  float4 outv[3];
  float4 psum = {0.f,0.f,0.f,0.f};
  #pragma unroll
  for (int q=0; q<3; q++){
    int n = o + q*64;
    float4 x = {0.f,0.f,0.f,0.f};
    if (n < NPG){
      float inv = 1.f / outf[n*36 + 32];
      float4 u = *(const float4*)&outf[n*36 + c8*4];
      x.x = u.x*inv + bs4.x;  x.y = u.y*inv + bs4.y;
      x.z = u.z*inv + bs4.z;  x.w = u.w*inv + bs4.w;
      x.x = (x.x>0.f)?x.x:(__expf(x.x)-1.f);
      x.y = (x.y>0.f)?x.y:(__expf(x.y)-1.f);
      x.z = (x.z>0.f)?x.z:(__expf(x.z)-1.f);
      x.w = (x.w>0.f)?x.w:(__expf(x.w)-1.f);
      psum.x+=x.x; psum.y+=x.y; psum.z+=x.z; psum.w+=x.w;
    }
    outv[q]=x;
  }
  psum.x += __shfl_xor(psum.x, 8, 32); psum.y += __shfl_xor(psum.y, 8, 32);
  psum.z += __shfl_xor(psum.z, 8, 32); psum.w += __shfl_xor(psum.w, 8, 32);
  psum.x += __shfl_xor(psum.x,16, 32); psum.y += __shfl_xor(psum.y,16, 32);
  psum.z += __shfl_xor(psum.z,16, 32); psum.w += __shfl_xor(psum.w,16, 32);
  if (sub==0 && lane32<8) ps[grp16][c8] = psum;
  __syncthreads();
  if (t < 8){
    float4 m = {0.f,0.f,0.f,0.f};
    #pragma unroll
    for (int q=0;q<16;q++){ float4 v=ps[q][t]; m.x+=v.x; m.y+=v.y; m.z+=v.z; m.w+=v.w; }
    m.x*=(1.f/152.f); m.y*=(1.f/152.f); m.z*=(1.f/152.f); m.w*=(1.f/152.f);
    mred4[t] = m;
  }
  __syncthreads();
  const float4 mean4 = mred4[c8];
  float4 v2 = {0.f,0.f,0.f,0.f};
  #pragma unroll
  for (int q=0;q<3;q++){
    int n = o + q*64;
    if (n < NPG){
      outv[q].x -= mean4.x*ms4.x; outv[q].y -= mean4.y*ms4.y;
      outv[q].z -= mean4.z*ms4.z; outv[q].w -= mean4.w*ms4.w;
      v2.x = fmaf(outv[q].x,outv[q].x,v2.x); v2.y = fmaf(outv[q].y,outv[q].y,v2.y);
      v2.z = fmaf(outv[q].z,outv[q].z,v2.z); v2.w = fmaf(outv[q].w,outv[q].w,v2.w);
    }
  }
  v2.x += __shfl_xor(v2.x, 8, 32); v2.y += __shfl_xor(v2.y, 8, 32);
  v2.z += __shfl_xor(v2.z, 8, 32); v2.w += __shfl_xor(v2.w, 8, 32);
  v2.x += __shfl_xor(v2.x,16, 32); v2.y += __shfl_xor(v2.y,16, 32);
  v2.z += __shfl_xor(v2.z,16, 32); v2.w += __shfl_xor(v2.w,16, 32);
  if (sub==0 && lane32<8) ps[grp16][c8] = v2;
  __syncthreads();
  if (t < 8){
    float4 s = {0.f,0.f,0.f,0.f};
    #pragma unroll
    for (int q=0;q<16;q++){ float4 v=ps[q][t]; s.x+=v.x; s.y+=v.y; s.z+=v.z; s.w+=v.w; }
    float4 rv;
    rv.x = rsqrtf(s.x*(1.f/152.f)+1e-5f); rv.y = rsqrtf(s.y*(1.f/152.f)+1e-5f);
    rv.z = rsqrtf(s.z*(1.f/152.f)+1e-5f); rv.w = rsqrtf(s.w*(1.f/152.f)+1e-5f);
    vred4[t] = rv;
  }
  __syncthreads();
  const float4 rs4 = vred4[c8];
  #pragma unroll
  for (int q=0;q<3;q++){
    int n = o + q*64;
    if (n < NPG){
      float4 x = outv[q];
      x.x = x.x*rs4.x*gw4.x + gb4.x;  x.y = x.y*rs4.y*gw4.y + gb4.y;
      x.z = x.z*rs4.z*gw4.z + gb4.z;  x.w = x.w*rs4.w*gw4.w + gb4.w;
      size_t oidx = (size_t)(base+n)*CCH + cb;
      if (OUT_BF16){
        ushort4v pk = { f2bf(x.x), f2bf(x.y), f2bf(x.z), f2bf(x.w) };
        *(ushort4v*)((unsigned short*)OUTp + oidx) = pk;
      } else {
        *(float4*)((float*)OUTp + oidx) = x;
      }
    }
  }
}

extern "C" void kernel_launch(void* const* d_in, const int* in_sizes, int n_in,
                              void* d_out, int out_size, void* d_ws, size_t ws_size,
                              hipStream_t stream){
  (void)in_sizes; (void)n_in; (void)out_size; (void)ws_size;
  const float* x    = (const float*)d_in[0];
  const int*   ei   = (const int*)  d_in[1];
  const float* W1   = (const float*)d_in[3];
  const float* as1  = (const float*)d_in[4];
  const float* ad1  = (const float*)d_in[5];
  const float* b1   = (const float*)d_in[6];
  const float* W2   = (const float*)d_in[7];
  const float* as2  = (const float*)d_in[8];
  const float* ad2  = (const float*)d_in[9];
  const float* b2   = (const float*)d_in[10];
  const float* gw1  = (const float*)d_in[11];
  const float* gb1  = (const float*)d_in[12];
  const float* gms1 = (const float*)d_in[13];
  const float* gw2  = (const float*)d_in[14];
  const float* gb2  = (const float*)d_in[15];
  const float* gms2 = (const float*)d_in[16];
  const int* esrc = ei;
  const int* edst = ei + NEDGE;

  char* ws = (char*)d_ws;
  unsigned short* Hbuf  = (unsigned short*)ws;                               // [N,192] bf16
  unsigned short* Obuf  = (unsigned short*)(ws + (size_t)NNODES*CCH*2);      // [N,192] bf16
  unsigned short* Wt1   = (unsigned short*)(ws + (size_t)NNODES*CCH*4);      // [192,128] bf16
  unsigned short* Wt2   = Wt1 + CCH*128;                                     // [192,192] bf16
  unsigned int*   gpack = (unsigned int*)(Wt2 + CCH*192);                    // [512,1368] u32

  pack_build<<<NGRAPH, 256, 0, stream>>>(esrc, edst, gpack);
  wprep_all<<<(CCH*(128+192)+255)/256, 256, 0, stream>>>(W1, W2, Wt1, Wt2);

  gemm_mfma<128,false><<<dim3(NNODES/64,2), 256, 0, stream>>>((const void*)x, Wt1, Hbuf);
  gat_fused<true><<<NGRAPH*HEADS, 512, 0, stream>>>(Hbuf, gpack, as1, ad1, b1, gw1, gb1, gms1, (void*)Obuf);
  gemm_mfma<192,true><<<dim3(NNODES/64,2), 256, 0, stream>>>((const void*)Obuf, Wt2, Hbuf);
  gat_fused<false><<<NGRAPH*HEADS, 512, 0, stream>>>(Hbuf, gpack, as2, ad2, b2, gw2, gb2, gms2, d_out);
}